// Round 11
// baseline (428.172 us; speedup 1.0000x reference)
//
#include <hip/hip_runtime.h>
#include <hip/hip_bf16.h>
#include <cstdint>
#include <cstddef>

#define NN 8192
#define FIN 256
#define FOUT 64
#define ALPHA_SLOPE 0.2f
#define EXP_M10 4.5399929762484854e-05f   // exp(-10)

#define JSPLIT 8
#define JRANGE (NN / JSPLIT)              // 1024
#define KITER (JRANGE / 32)               // 32
#define RB 128                            // rows per block (8 waves x 16)
#define HT_PITCH 2064                     // bytes per htg row in LDS (2048 + 16; 516 words -> only 2-way bank alias = free)
#define CP 68                             // slab column pitch (floats)

typedef short s16x8 __attribute__((ext_vector_type(8)));
typedef float f32x4 __attribute__((ext_vector_type(4)));
typedef int   i32x4 __attribute__((ext_vector_type(4)));

__device__ __forceinline__ unsigned short f2bf(float x) {
    union { float f; uint32_t u; } v; v.f = x;
    uint32_t u = v.u;
    return (unsigned short)((u + 0x7FFFu + ((u >> 16) & 1u)) >> 16);  // RNE
}

// round two floats to bf16 (RNE), accumulate the ROUNDED values into dsum
// (denominator exactly matches the bf16 numerator weights)
__device__ __forceinline__ unsigned int rpack2(float a, float b, float& dsum) {
    union { float f; uint32_t u; } va, vb, ra, rb;
    va.f = a; vb.f = b;
    ra.u = (va.u + 0x7FFFu + ((va.u >> 16) & 1u)) & 0xFFFF0000u;
    rb.u = (vb.u + 0x7FFFu + ((vb.u >> 16) & 1u)) & 0xFFFF0000u;
    dsum += ra.f + rb.f;
    return (ra.u >> 16) | rb.u;
}

__device__ __forceinline__ float wval(int a, float s2v, float s1v) {
    float x = s1v + s2v;
    return (a > 0) ? __expf(fmaxf(x, ALPHA_SLOPE * x)) : EXP_M10;
}

// ---------------- Kernel 1: h = input@W, s1 = h@a1, s2 = h@a2, htg = bf16(h)^T ----
__global__ __launch_bounds__(256) void k_h(
    const float* __restrict__ input, const float* __restrict__ W,
    const float* __restrict__ a,
    unsigned short* __restrict__ htg, float* __restrict__ s1, float* __restrict__ s2)
{
    __shared__ __align__(16) unsigned short tile[64][28];
    const int wid  = threadIdx.x >> 6;
    const int lane = threadIdx.x & 63;
    const int i0   = blockIdx.x * 16;
    const int r0   = wid * 4;
    const float* inb = input + (size_t)(i0 + r0) * FIN;

    float acc0 = 0.f, acc1 = 0.f, acc2 = 0.f, acc3 = 0.f;
    #pragma unroll 4
    for (int c = 0; c < FIN; c += 4) {
        float w0 = W[(c + 0) * FOUT + lane];
        float w1 = W[(c + 1) * FOUT + lane];
        float w2 = W[(c + 2) * FOUT + lane];
        float w3 = W[(c + 3) * FOUT + lane];
        float4 x0 = *(const float4*)(inb + 0 * FIN + c);
        float4 x1 = *(const float4*)(inb + 1 * FIN + c);
        float4 x2 = *(const float4*)(inb + 2 * FIN + c);
        float4 x3 = *(const float4*)(inb + 3 * FIN + c);
        acc0 = fmaf(x0.x, w0, fmaf(x0.y, w1, fmaf(x0.z, w2, fmaf(x0.w, w3, acc0))));
        acc1 = fmaf(x1.x, w0, fmaf(x1.y, w1, fmaf(x1.z, w2, fmaf(x1.w, w3, acc1))));
        acc2 = fmaf(x2.x, w0, fmaf(x2.y, w1, fmaf(x2.z, w2, fmaf(x2.w, w3, acc2))));
        acc3 = fmaf(x3.x, w0, fmaf(x3.y, w1, fmaf(x3.z, w2, fmaf(x3.w, w3, acc3))));
    }

    const float a1v = a[lane], a2v = a[FOUT + lane];
    float accs[4] = {acc0, acc1, acc2, acc3};
    #pragma unroll
    for (int r = 0; r < 4; ++r) {
        float v1 = accs[r] * a1v;
        float v2 = accs[r] * a2v;
        #pragma unroll
        for (int off = 32; off; off >>= 1) {
            v1 += __shfl_xor(v1, off);
            v2 += __shfl_xor(v2, off);
        }
        if (lane == 0) { s1[i0 + r0 + r] = v1; s2[i0 + r0 + r] = v2; }
        tile[lane][r0 + r] = f2bf(accs[r]);
    }
    __syncthreads();

    const int feat = threadIdx.x >> 2;
    const int cg   = (threadIdx.x & 3) * 4;
    uint2 q = *(const uint2*)&tile[feat][cg];
    *(uint2*)(htg + (size_t)feat * NN + i0 + cg) = q;
}

// ---------------- Kernel 2: barrier-free fused attention ---------------------------
// Block: 128 rows x 1024-col j-range, 512 threads (8 waves), 136 KB LDS, 1 blk/CU.
// Prologue stages the block's full htg slice (64 feats x 1024 cols) + s2 range
// into read-only LDS; ONE barrier; then each wave streams its 16 rows x 1024 cols
// with ZERO further barriers: A-fragment w=exp(masked lrelu) computed in-register
// from fragment-exact coalesced adj loads (lane=row, 2 x dwordx4 per kk), B-frags
// from LDS, 4 MFMA per kk (all 64 feats), denominator = in-register dsum of the
// ROUNDED bf16 weights (quad-shuffle-reduced). Compiler can pipeline the 32-iter
// loop arbitrarily deep: no barrier drains, ~full VGPR budget at 1 block/CU.
__global__ __launch_bounds__(512) void k_attn(
    const int* __restrict__ adj,
    const unsigned short* __restrict__ htg,
    const float* __restrict__ s1g, const float* __restrict__ s2g,
    float* __restrict__ slabs)
{
    __shared__ __align__(16) unsigned char hlds[64 * HT_PITCH];   // 132096 B
    __shared__ __align__(16) float s2buf[JRANGE];                 // 4096 B

    const int t    = threadIdx.x;
    const int wid  = t >> 6;
    const int lane = t & 63;
    const int bi   = blockIdx.x >> 3;
    const int js   = blockIdx.x & 7;
    const int i0   = bi * RB;
    const int jbase = js * JRANGE;
    const int m    = lane & 15;
    const int quad = lane >> 4;

    // ---- prologue: stage htg slice (64 x 1024 bf16) + s2 range, one barrier ----
    #pragma unroll
    for (int c = t; c < 64 * (JRANGE / 8); c += 512) {   // 8192 16B-chunks
        const int row = c >> 7;
        const int col = c & 127;
        *(s16x8*)&hlds[row * HT_PITCH + col * 16] =
            *(const s16x8*)(htg + (size_t)row * NN + jbase + col * 8);
    }
    if (t < JRANGE / 4)
        *(float4*)&s2buf[t * 4] = *(const float4*)(s2g + jbase + t * 4);
    __syncthreads();

    // ---- barrier-free main loop: wave wid owns rows i0+wid*16 .. +15 ----
    const int irow = i0 + wid * 16 + m;
    const float s1v = s1g[irow];
    const int* ap = adj + (size_t)irow * NN + jbase + quad * 8;

    f32x4 acc0 = {0,0,0,0}, acc1 = {0,0,0,0}, acc2 = {0,0,0,0}, acc3 = {0,0,0,0};
    float dsum = 0.f;

    #pragma unroll 4
    for (int kk = 0; kk < KITER; ++kk) {
        i32x4 a0 = *(const i32x4*)(ap + kk * 32);
        i32x4 a1 = *(const i32x4*)(ap + kk * 32 + 4);

        const int cb = (kk * 32 + quad * 8) * 2;          // byte col offset in LDS
        s16x8 b0 = *(const s16x8*)&hlds[(m +  0) * HT_PITCH + cb];
        s16x8 b1 = *(const s16x8*)&hlds[(m + 16) * HT_PITCH + cb];
        s16x8 b2 = *(const s16x8*)&hlds[(m + 32) * HT_PITCH + cb];
        s16x8 b3 = *(const s16x8*)&hlds[(m + 48) * HT_PITCH + cb];
        float4 v0 = *(const float4*)&s2buf[kk * 32 + quad * 8];
        float4 v1 = *(const float4*)&s2buf[kk * 32 + quad * 8 + 4];

        union { uint4 u; s16x8 v; } af;
        af.u.x = rpack2(wval(a0.x, v0.x, s1v), wval(a0.y, v0.y, s1v), dsum);
        af.u.y = rpack2(wval(a0.z, v0.z, s1v), wval(a0.w, v0.w, s1v), dsum);
        af.u.z = rpack2(wval(a1.x, v1.x, s1v), wval(a1.y, v1.y, s1v), dsum);
        af.u.w = rpack2(wval(a1.z, v1.z, s1v), wval(a1.w, v1.w, s1v), dsum);

        acc0 = __builtin_amdgcn_mfma_f32_16x16x32_bf16(af.v, b0, acc0, 0, 0, 0);
        acc1 = __builtin_amdgcn_mfma_f32_16x16x32_bf16(af.v, b1, acc1, 0, 0, 0);
        acc2 = __builtin_amdgcn_mfma_f32_16x16x32_bf16(af.v, b2, acc2, 0, 0, 0);
        acc3 = __builtin_amdgcn_mfma_f32_16x16x32_bf16(af.v, b3, acc3, 0, 0, 0);
    }

    // ---- epilogue: direct slab writes; quad-reduce dsum for the denominator ----
    float* slab = slabs + (size_t)js * ((size_t)NN * CP);
    const int r0 = i0 + wid * 16 + quad * 4;
    #pragma unroll
    for (int reg = 0; reg < 4; ++reg) {
        size_t ro = (size_t)(r0 + reg) * CP;
        slab[ro +  0 + m] = acc0[reg];
        slab[ro + 16 + m] = acc1[reg];
        slab[ro + 32 + m] = acc2[reg];
        slab[ro + 48 + m] = acc3[reg];
    }
    // lanes {m, m+16, m+32, m+48} share row irow: reduce their column partials
    dsum += __shfl_xor(dsum, 16);
    dsum += __shfl_xor(dsum, 32);
    if (quad == 0) slab[(size_t)irow * CP + 64] = dsum;
}

// ---------------- Kernel 3: reduce splits, normalize, ELU --------------------------
__global__ __launch_bounds__(256) void k_norm(
    const float* __restrict__ slabs, float* __restrict__ out)
{
    int gid = blockIdx.x * 256 + threadIdx.x;
    int i = gid >> 6, k = gid & 63;
    float num = 0.f, den = 0.f;
    #pragma unroll
    for (int js = 0; js < JSPLIT; ++js) {
        const float* row = slabs + (size_t)js * ((size_t)NN * CP) + (size_t)i * CP;
        num += row[k];
        den += row[64];
    }
    float v = num / den;
    out[gid] = (v > 0.f) ? v : (__expf(v) - 1.f);
}

// ---------------- launch -----------------------------------------------------------
extern "C" void kernel_launch(void* const* d_in, const int* in_sizes, int n_in,
                              void* d_out, int out_size, void* d_ws, size_t ws_size,
                              hipStream_t stream) {
    const float* input = (const float*)d_in[0];
    const int*   adj   = (const int*)d_in[1];
    const float* W     = (const float*)d_in[2];
    const float* a     = (const float*)d_in[3];
    float* out = (float*)d_out;

    char* ws = (char*)d_ws;
    float* slabs = (float*)ws;
    size_t off = (size_t)JSPLIT * NN * CP * sizeof(float);      // 17.8 MB
    unsigned short* htg = (unsigned short*)(ws + off);
    off += (size_t)FOUT * NN * sizeof(unsigned short);          // 1 MB
    float* s1 = (float*)(ws + off); off += NN * sizeof(float);
    float* s2 = (float*)(ws + off);

    k_h   <<<NN / 16, 256, 0, stream>>>(input, W, a, htg, s1, s2);
    k_attn<<<(NN / RB) * JSPLIT, 512, 0, stream>>>(adj, htg, s1, s2, slabs);
    k_norm<<<NN * FOUT / 256, 256, 0, stream>>>(slabs, out);
}